// Round 8
// baseline (3547.337 us; speedup 1.0000x reference)
//
#include <hip/hip_runtime.h>
#include <hip/hip_bf16.h>
#include <math.h>

// Sizes
#define BB 256
#define SS 64
#define EE 300
#define EP 304   // padded embed
#define KK9 816  // EP + HH (concat K for fused LSTM gemm)
#define VV 30000
#define HH 512
#define H2 1024
#define DA 350
#define RR 8
#define CC 150
#define PP 16
#define CP 2400

// Output layout (elements, fp32)
#define ATT_OFF    0L
#define CL_OFF     131072L
#define PRED_OFF   169472L
#define ROUTES_OFF 5084672L

static __device__ __forceinline__ float sigm8(float x) { return 1.0f / (1.0f + expf(-x)); }

// ---------------------------------------------------------------------------
// X[s][b][EP] = embedding[ids[b][s]][:], zero-padded cols 300..303
// ---------------------------------------------------------------------------
__global__ __launch_bounds__(256) void k_gather8(
    const int* __restrict__ ids, const float* __restrict__ emb, float* __restrict__ X)
{
    const long idx = (long)blockIdx.x * 256 + threadIdx.x;
    if (idx >= (long)SS * BB * EP) return;
    const int row = (int)(idx / EP), e = (int)(idx % EP);
    const int s = row >> 8, b = row & 255;
    int tok = ids[(long)b * SS + s];
    if ((unsigned)tok >= (unsigned)VV) tok = 0;
    X[idx] = (e < EE) ? emb[(long)tok * EE + e] : 0.0f;
}

// WpI[dir][j2][k], j2 = unit*4 + gate (gate-interleaved rows):
//   k<300: wih[gate*512+unit][k]; 300..303: 0; else whh[gate*512+unit][k-304]
__global__ __launch_bounds__(256) void k_packw8(
    const float* __restrict__ wihF, const float* __restrict__ whhF,
    const float* __restrict__ wihB, const float* __restrict__ whhB,
    float* __restrict__ WpI)
{
    const long idx = (long)blockIdx.x * 256 + threadIdx.x;
    if (idx >= (long)2 * 2048 * KK9) return;
    const int dir = (int)(idx / (2048 * KK9));
    const int rem = (int)(idx % (2048 * KK9));
    const int j2 = rem / KK9, k = rem % KK9;
    const int u = j2 >> 2, g = j2 & 3;
    const int srow = g * HH + u;
    const float* wih = dir ? wihB : wihF;
    const float* whh = dir ? whhB : whhF;
    float v;
    if (k < EE)       v = wih[(long)srow * EE + k];
    else if (k < EP)  v = 0.0f;
    else              v = whh[(long)srow * HH + (k - EP)];
    WpI[idx] = v;
}

// biasI[dir][j2] = bih[g*512+u] + bhh[g*512+u], interleaved
__global__ __launch_bounds__(256) void k_packb8(
    const float* __restrict__ bihF, const float* __restrict__ bhhF,
    const float* __restrict__ bihB, const float* __restrict__ bhhB,
    float* __restrict__ biasI)
{
    const int idx = blockIdx.x * 256 + threadIdx.x;
    if (idx >= 2 * 2048) return;
    const int dir = idx >> 11, j2 = idx & 2047;
    const int u = j2 >> 2, g = j2 & 3;
    const int srow = g * HH + u;
    biasI[idx] = dir ? (bihB[srow] + bhhB[srow]) : (bihF[srow] + bhhF[srow]);
}

// ---------------------------------------------------------------------------
// Fused LSTM step: z-tile GEMM (A = [X_s | h_prev], B = WpI^T) + gate epilogue.
// 64x64 tile, BK=16. Gate-interleaved cols => each thread's acc[i][0..3] are
// (i,f,g,o) of one (batch,unit). Epilogue updates c and writes h directly.
// grid (32, 4, 2) = 256 blocks.
// ---------------------------------------------------------------------------
__global__ __launch_bounds__(256) void k_lstm_step8(
    const float* __restrict__ X, float* __restrict__ hs,
    const float* __restrict__ WpI, const float* __restrict__ biasI,
    float* __restrict__ cbuf, int step)
{
    __shared__ float As[16][68];
    __shared__ float Bs[16][68];
    const int dir = blockIdx.z;
    const int n0 = blockIdx.x * 64;
    const int m0 = blockIdx.y * 64;
    const int s_eff  = dir ? (SS - 1 - step) : step;
    const int s_prev = dir ? (s_eff + 1) : (s_eff - 1);
    const float* Xs = X + (long)s_eff * BB * EP;
    const float* W  = WpI + (long)dir * 2048 * KK9;
    const int tid = threadIdx.x;
    const int ty = tid >> 4, tx = tid & 15;
    float acc[4][4] = {};

    const int KT = (step == 0) ? 19 : 51;
    for (int t = 0; t < KT; ++t) {
        const int k0 = t * 16;
        {
            const int i = tid >> 2, kk = (tid & 3) * 4;
            const int row = m0 + i;
            float4 v;
            if (t < 19)
                v = *(const float4*)(Xs + (long)row * EP + k0 + kk);
            else
                v = *(const float4*)(hs + ((long)row * SS + s_prev) * H2
                                      + dir * HH + (k0 - EP) + kk);
            As[kk][i] = v.x; As[kk + 1][i] = v.y; As[kk + 2][i] = v.z; As[kk + 3][i] = v.w;
        }
        {
            const int j = tid >> 2, kk = (tid & 3) * 4;
            const float4 v = *(const float4*)(W + (long)(n0 + j) * KK9 + k0 + kk);
            Bs[kk][j] = v.x; Bs[kk + 1][j] = v.y; Bs[kk + 2][j] = v.z; Bs[kk + 3][j] = v.w;
        }
        __syncthreads();
        #pragma unroll
        for (int k = 0; k < 16; ++k) {
            const float4 av = *(const float4*)&As[k][ty * 4];
            const float4 bv = *(const float4*)&Bs[k][tx * 4];
            const float a4[4] = {av.x, av.y, av.z, av.w};
            const float b4[4] = {bv.x, bv.y, bv.z, bv.w};
            #pragma unroll
            for (int i = 0; i < 4; ++i)
                #pragma unroll
                for (int j = 0; j < 4; ++j)
                    acc[i][j] = fmaf(a4[i], b4[j], acc[i][j]);
        }
        __syncthreads();
    }

    // Gate epilogue: unit = n0/4 + tx; rows = batch m0+ty*4+i
    const int u = (n0 >> 2) + tx;
    const float* bI = biasI + dir * 2048 + u * 4;
    const float b0 = bI[0], b1 = bI[1], b2 = bI[2], b3 = bI[3];
    #pragma unroll
    for (int i = 0; i < 4; ++i) {
        const int brow = m0 + ty * 4 + i;
        const float zi = acc[i][0] + b0;
        const float zf = acc[i][1] + b1;
        const float zg = acc[i][2] + b2;
        const float zo = acc[i][3] + b3;
        float* cp = cbuf + ((long)dir * BB + brow) * HH + u;
        float c = (step > 0) ? *cp : 0.0f;
        c = sigm8(zf) * c + sigm8(zi) * tanhf(zg);
        *cp = c;
        hs[((long)brow * SS + s_eff) * H2 + dir * HH + u] = sigm8(zo) * tanhf(c);
    }
}

// ---------------------------------------------------------------------------
// Generic fp32 tiled GEMM (validated). BT=1: B as [N][K]; BT=0: B as [K][N].
// ACT=1: tanh epilogue.
// ---------------------------------------------------------------------------
template<int BT, int ACT>
__global__ __launch_bounds__(256) void k_gemm8(
    const float* __restrict__ A, long lda, long sAz,
    const float* __restrict__ Bm, long ldb, long sBz,
    float* __restrict__ Cf, long ldc, long sCz, int N, int K)
{
    __shared__ float As[16][68];
    __shared__ float Bs[16][68];
    const int n0 = blockIdx.x * 64;
    const int m0 = blockIdx.y * 64;
    const float* Ab = A + (long)blockIdx.z * sAz;
    const float* Bb = Bm + (long)blockIdx.z * sBz;
    const int tid = threadIdx.x;
    const int ty = tid >> 4, tx = tid & 15;
    float acc[4][4] = {};

    for (int k0 = 0; k0 < K; k0 += 16) {
        {
            const int i = tid >> 2, kk = (tid & 3) * 4;
            const float4 v = *(const float4*)(Ab + (long)(m0 + i) * lda + k0 + kk);
            As[kk][i] = v.x; As[kk + 1][i] = v.y; As[kk + 2][i] = v.z; As[kk + 3][i] = v.w;
        }
        if (BT) {
            const int j = tid >> 2, kk = (tid & 3) * 4;
            const int n = n0 + j;
            float4 v = make_float4(0.f, 0.f, 0.f, 0.f);
            if (n < N) v = *(const float4*)(Bb + (long)n * ldb + k0 + kk);
            Bs[kk][j] = v.x; Bs[kk + 1][j] = v.y; Bs[kk + 2][j] = v.z; Bs[kk + 3][j] = v.w;
        } else {
            const int kk = tid >> 4, jj = (tid & 15) * 4;
            const int n = n0 + jj;
            float4 v = make_float4(0.f, 0.f, 0.f, 0.f);
            if (n + 3 < N) {
                v = *(const float4*)(Bb + (long)(k0 + kk) * ldb + n);
            } else {
                const float* src = Bb + (long)(k0 + kk) * ldb + n;
                if (n < N)     v.x = src[0];
                if (n + 1 < N) v.y = src[1];
                if (n + 2 < N) v.z = src[2];
            }
            *(float4*)&Bs[kk][jj] = v;
        }
        __syncthreads();
        #pragma unroll
        for (int k = 0; k < 16; ++k) {
            const float4 av = *(const float4*)&As[k][ty * 4];
            const float4 bv = *(const float4*)&Bs[k][tx * 4];
            const float a4[4] = {av.x, av.y, av.z, av.w};
            const float b4[4] = {bv.x, bv.y, bv.z, bv.w};
            #pragma unroll
            for (int i = 0; i < 4; ++i)
                #pragma unroll
                for (int j = 0; j < 4; ++j)
                    acc[i][j] = fmaf(a4[i], b4[j], acc[i][j]);
        }
        __syncthreads();
    }

    const long zc = (long)blockIdx.z * sCz;
    #pragma unroll
    for (int i = 0; i < 4; ++i) {
        const int m = m0 + ty * 4 + i;
        #pragma unroll
        for (int j = 0; j < 4; ++j) {
            const int n = n0 + tx * 4 + j;
            if (n < N) {
                float val = acc[i][j];
                if (ACT == 1) val = tanhf(val);
                Cf[zc + (long)m * ldc + n] = val;
            }
        }
    }
}

// attlog[b,r,s] = sum_a pre[b,s,a] * ws2[r,a]
__global__ __launch_bounds__(256) void attlog8(
    const float* __restrict__ pre, const float* __restrict__ ws2,
    float* __restrict__ attlog)
{
    const int idx = blockIdx.x * 256 + threadIdx.x;
    if (idx >= BB * RR * SS) return;
    const int s = idx & 63, r = (idx >> 6) & 7, b = idx >> 9;
    const float* p = pre + ((long)b * SS + s) * DA;
    const float* w = ws2 + (long)r * DA;
    float acc = 0.0f;
    for (int a = 0; a < DA; ++a) acc = fmaf(p[a], w[a], acc);
    attlog[idx] = acc;
}

// softmax over s per (b,r)
__global__ __launch_bounds__(256) void soft8(
    const float* __restrict__ attlog, float* __restrict__ att_out)
{
    const int idx = blockIdx.x * 256 + threadIdx.x;
    if (idx >= BB * RR) return;
    const float* L = attlog + (long)idx * SS;
    float mx = L[0];
    for (int s = 1; s < SS; ++s) mx = fmaxf(mx, L[s]);
    float sm = 0.0f;
    for (int s = 0; s < SS; ++s) sm += expf(L[s] - mx);
    for (int s = 0; s < SS; ++s)
        att_out[(long)idx * SS + s] = expf(L[s] - mx) / sm;
}

// sem[b,r,d] = sum_s att[b,r,s] * hs[b][s][d]
__global__ __launch_bounds__(256) void sem8(
    const float* __restrict__ att, const float* __restrict__ hs,
    float* __restrict__ sem)
{
    const long idx = (long)blockIdx.x * 256 + threadIdx.x;
    if (idx >= (long)BB * RR * H2) return;
    const int d = (int)(idx & 1023);
    const int r = (int)((idx >> 10) & 7);
    const int b = (int)(idx >> 13);
    const float* aw = att + ((long)b * RR + r) * SS;
    float acc = 0.0f;
    for (int s = 0; s < SS; ++s)
        acc = fmaf(aw[s], hs[((long)b * SS + s) * H2 + d], acc);
    sem[idx] = acc;
}

// ---------------------------------------------------------------------------
// Dynamic routing
// ---------------------------------------------------------------------------
__global__ __launch_bounds__(256) void route8(
    const float* __restrict__ pred,
    float* __restrict__ cls_out, float* __restrict__ routes_out)
{
    __shared__ float predS[RR * CP];
    __shared__ float logitS[RR * CC];
    __shared__ float routeS[RR * CC];
    __shared__ float preactS[CP];
    __shared__ float vS[CP];
    __shared__ float scaleS[CC];
    __shared__ float rmax[RR], rsum[RR];
    const int b = blockIdx.x, tid = threadIdx.x;
    const float* ps = pred + (long)b * RR * CP;
    for (int i = tid; i < RR * CP; i += 256) predS[i] = ps[i];
    for (int i = tid; i < RR * CC; i += 256) logitS[i] = 0.0f;
    __syncthreads();

    for (int it = 0; it < 3; ++it) {
        if (tid < RR) {
            float mx = -1e30f;
            for (int c = 0; c < CC; ++c) mx = fmaxf(mx, logitS[tid * CC + c]);
            float sm = 0.0f;
            for (int c = 0; c < CC; ++c) sm += expf(logitS[tid * CC + c] - mx);
            rmax[tid] = mx; rsum[tid] = sm;
        }
        __syncthreads();
        for (int i = tid; i < RR * CC; i += 256) {
            const int r = i / CC;
            routeS[i] = expf(logitS[i] - rmax[r]) / rsum[r];
        }
        __syncthreads();
        for (int cp = tid; cp < CP; cp += 256) {
            const int c = cp >> 4;
            float a = 0.0f;
            #pragma unroll
            for (int r = 0; r < RR; ++r)
                a = fmaf(routeS[r * CC + c], predS[r * CP + cp], a);
            preactS[cp] = a;
        }
        __syncthreads();
        for (int c = tid; c < CC; c += 256) {
            float n2 = 0.0f;
            #pragma unroll
            for (int p = 0; p < PP; ++p) { const float x = preactS[c * PP + p]; n2 = fmaf(x, x, n2); }
            scaleS[c] = (n2 / (1.0f + n2)) / sqrtf(n2 + 1e-9f);
        }
        __syncthreads();
        for (int cp = tid; cp < CP; cp += 256) vS[cp] = preactS[cp] * scaleS[cp >> 4];
        __syncthreads();
        for (int i = tid; i < RR * CC; i += 256) {
            const int r = i / CC, c = i % CC;
            float a = 0.0f;
            #pragma unroll
            for (int p = 0; p < PP; ++p)
                a = fmaf(predS[r * CP + c * PP + p], vS[c * PP + p], a);
            logitS[i] += a;
        }
        __syncthreads();
    }

    for (int i = tid; i < RR * CC; i += 256)
        routes_out[(long)b * RR * CC + i] = routeS[i];
    for (int c = tid; c < CC; c += 256) {
        float n2 = 0.0f;
        #pragma unroll
        for (int p = 0; p < PP; ++p) { const float x = vS[c * PP + p]; n2 = fmaf(x, x, n2); }
        cls_out[(long)b * CC + c] = sqrtf(n2);
    }
}

// ---------------------------------------------------------------------------
extern "C" void kernel_launch(void* const* d_in, const int* in_sizes, int n_in,
                              void* d_out, int out_size, void* d_ws, size_t ws_size,
                              hipStream_t stream)
{
    (void)in_sizes; (void)n_in; (void)out_size;
    const int*   ids   = (const int*)d_in[0];
    const float* emb   = (const float*)d_in[2];
    const float* wih_f = (const float*)d_in[3];
    const float* whh_f = (const float*)d_in[4];
    const float* bih_f = (const float*)d_in[5];
    const float* bhh_f = (const float*)d_in[6];
    const float* wih_b = (const float*)d_in[7];
    const float* whh_b = (const float*)d_in[8];
    const float* bih_b = (const float*)d_in[9];
    const float* bhh_b = (const float*)d_in[10];
    const float* ws1   = (const float*)d_in[11];
    const float* ws2   = (const float*)d_in[12];
    const float* caps  = (const float*)d_in[13];
    float* out = (float*)d_out;   // fp32 outputs

    // Workspace: hs | cbuf | region1 (X,WpI,biasI -> pre,sem) | attlog
    float* ws   = (float*)d_ws;
    float* hs   = ws;                         // [256][64][1024] = 16,777,216
    float* cbuf = hs + 16777216;              // [2][256][512]   =    262,144
    float* region1 = cbuf + 262144;           // 8,327,168
    float* X     = region1;                   // [64][256][304]  =  4,980,736
    float* WpI   = region1 + 4980736;         // [2][2048][816]  =  3,342,336
    float* biasI = region1 + 8323072;         // [2][2048]       =      4,096
    float* pre   = region1;                   // [256][64][350]  =  5,734,400 (after LSTM)
    float* sem   = region1 + 5734400;         // [256][8][1024]  =  2,097,152
    float* attlog = region1 + 8327168;        //    131,072
    const size_t need = (size_t)(16777216 + 262144 + 8327168 + 131072) * 4;
    if (ws_size < need) return;

    // Stage inputs
    k_gather8<<<(int)(((long)SS * BB * EP + 255) / 256), 256, 0, stream>>>(ids, emb, X);
    k_packw8<<<(int)(((long)2 * 2048 * KK9 + 255) / 256), 256, 0, stream>>>(
        wih_f, whh_f, wih_b, whh_b, WpI);
    k_packb8<<<16, 256, 0, stream>>>(bih_f, bhh_f, bih_b, bhh_b, biasI);

    // Bidirectional LSTM: one fused kernel per step (GEMM + gates epilogue)
    for (int step = 0; step < SS; ++step)
        k_lstm_step8<<<dim3(32, 4, 2), 256, 0, stream>>>(X, hs, WpI, biasI, cbuf, step);

    // pre = tanh(hs @ ws1^T)  [M=16384, N=350, K=1024]
    {
        dim3 g((DA + 63) / 64, (BB * SS) / 64, 1);
        k_gemm8<1, 1><<<g, 256, 0, stream>>>(hs, H2, 0, ws1, H2, 0,
                                             pre, DA, 0, DA, H2);
    }

    attlog8<<<512, 256, 0, stream>>>(pre, ws2, attlog);
    soft8<<<8, 256, 0, stream>>>(attlog, out + ATT_OFF);
    sem8<<<8192, 256, 0, stream>>>(out + ATT_OFF, hs, sem);

    // pred[b,r,:] = sem[b,r,:] @ caps[r]  [M=256, N=2400, K=1024] x8 (z=r)
    {
        dim3 g((CP + 63) / 64, BB / 64, RR);
        k_gemm8<0, 0><<<g, 256, 0, stream>>>(sem, (long)RR * H2, H2,
                                             caps, CP, (long)H2 * CP,
                                             out + PRED_OFF, (long)RR * CP, CP, CP, H2);
    }

    route8<<<BB, 256, 0, stream>>>(out + PRED_OFF, out + CL_OFF, out + ROUTES_OFF);
}

// Round 9
// 3054.661 us; speedup vs baseline: 1.1613x; 1.1613x over previous
//
#include <hip/hip_runtime.h>
#include <hip/hip_bf16.h>
#include <math.h>

// Sizes
#define BB 256
#define SS 64
#define EE 300
#define EP 304   // padded embed
#define KK9 816  // EP + HH (concat K for fused LSTM gemm)
#define VV 30000
#define HH 512
#define H2 1024
#define DA 350
#define RR 8
#define CC 150
#define PP 16
#define CP 2400

// Output layout (elements, fp32)
#define ATT_OFF    0L
#define CL_OFF     131072L
#define PRED_OFF   169472L
#define ROUTES_OFF 5084672L

static __device__ __forceinline__ float sigm9(float x) { return 1.0f / (1.0f + expf(-x)); }

// ---------------------------------------------------------------------------
// X[s][b][EP] = embedding[ids[b][s]][:], zero-padded cols 300..303
// ---------------------------------------------------------------------------
__global__ __launch_bounds__(256) void k_gather9(
    const int* __restrict__ ids, const float* __restrict__ emb, float* __restrict__ X)
{
    const long idx = (long)blockIdx.x * 256 + threadIdx.x;
    if (idx >= (long)SS * BB * EP) return;
    const int row = (int)(idx / EP), e = (int)(idx % EP);
    const int s = row >> 8, b = row & 255;
    int tok = ids[(long)b * SS + s];
    if ((unsigned)tok >= (unsigned)VV) tok = 0;
    X[idx] = (e < EE) ? emb[(long)tok * EE + e] : 0.0f;
}

// WpI[dir][j2][k], j2 = unit*4 + gate (gate-interleaved rows):
//   k<300: wih[gate*512+unit][k]; 300..303: 0; else whh[gate*512+unit][k-304]
__global__ __launch_bounds__(256) void k_packw9(
    const float* __restrict__ wihF, const float* __restrict__ whhF,
    const float* __restrict__ wihB, const float* __restrict__ whhB,
    float* __restrict__ WpI)
{
    const long idx = (long)blockIdx.x * 256 + threadIdx.x;
    if (idx >= (long)2 * 2048 * KK9) return;
    const int dir = (int)(idx / (2048 * KK9));
    const int rem = (int)(idx % (2048 * KK9));
    const int j2 = rem / KK9, k = rem % KK9;
    const int u = j2 >> 2, g = j2 & 3;
    const int srow = g * HH + u;
    const float* wih = dir ? wihB : wihF;
    const float* whh = dir ? whhB : whhF;
    float v;
    if (k < EE)       v = wih[(long)srow * EE + k];
    else if (k < EP)  v = 0.0f;
    else              v = whh[(long)srow * HH + (k - EP)];
    WpI[idx] = v;
}

// biasI[dir][j2] = bih[g*512+u] + bhh[g*512+u], interleaved
__global__ __launch_bounds__(256) void k_packb9(
    const float* __restrict__ bihF, const float* __restrict__ bhhF,
    const float* __restrict__ bihB, const float* __restrict__ bhhB,
    float* __restrict__ biasI)
{
    const int idx = blockIdx.x * 256 + threadIdx.x;
    if (idx >= 2 * 2048) return;
    const int dir = idx >> 11, j2 = idx & 2047;
    const int u = j2 >> 2, g = j2 & 3;
    const int srow = g * HH + u;
    biasI[idx] = dir ? (bihB[srow] + bhhB[srow]) : (bihF[srow] + bhhF[srow]);
}

// ---------------------------------------------------------------------------
// Fused LSTM step: 32x64 tile (2x4 per thread), grid (32,8,2) = 512 blocks
// = 2 blocks/CU = 8 waves/CU (latency hiding; round-8 version had 1 wave/SIMD).
// Gate-interleaved cols => each thread's acc[i][0..3] = (i,f,g,o) of one unit.
// ---------------------------------------------------------------------------
__global__ __launch_bounds__(256) void k_lstm_step9(
    const float* __restrict__ X, float* __restrict__ hs,
    const float* __restrict__ WpI, const float* __restrict__ biasI,
    float* __restrict__ cbuf, int step)
{
    __shared__ float As[16][36];
    __shared__ float Bs[16][68];
    const int dir = blockIdx.z;
    const int n0 = blockIdx.x * 64;
    const int m0 = blockIdx.y * 32;
    const int s_eff  = dir ? (SS - 1 - step) : step;
    const int s_prev = dir ? (s_eff + 1) : (s_eff - 1);
    const float* Xs = X + (long)s_eff * BB * EP;
    const float* W  = WpI + (long)dir * 2048 * KK9;
    const int tid = threadIdx.x;
    const int ty = tid >> 4, tx = tid & 15;   // ty 0..15 (row pair), tx 0..15 (col quad)
    float acc[2][4] = {};

    const int arow = tid >> 3;            // 0..31
    const int akk  = (tid & 7) * 2;       // 0..14
    const int bj   = tid >> 2;            // 0..63
    const int bkk  = (tid & 3) * 4;       // 0..12

    const int KT = (step == 0) ? 19 : 51;
    for (int t = 0; t < KT; ++t) {
        const int k0 = t * 16;
        {
            float2 v;
            if (t < 19)
                v = *(const float2*)(Xs + (long)(m0 + arow) * EP + k0 + akk);
            else
                v = *(const float2*)(hs + ((long)(m0 + arow) * SS + s_prev) * H2
                                      + dir * HH + (k0 - EP) + akk);
            As[akk][arow] = v.x; As[akk + 1][arow] = v.y;
        }
        {
            const float4 v = *(const float4*)(W + (long)(n0 + bj) * KK9 + k0 + bkk);
            Bs[bkk][bj] = v.x; Bs[bkk + 1][bj] = v.y;
            Bs[bkk + 2][bj] = v.z; Bs[bkk + 3][bj] = v.w;
        }
        __syncthreads();
        #pragma unroll
        for (int k = 0; k < 16; ++k) {
            const float2 av = *(const float2*)&As[k][ty * 2];
            const float4 bv = *(const float4*)&Bs[k][tx * 4];
            const float a2[2] = {av.x, av.y};
            const float b4[4] = {bv.x, bv.y, bv.z, bv.w};
            #pragma unroll
            for (int i = 0; i < 2; ++i)
                #pragma unroll
                for (int j = 0; j < 4; ++j)
                    acc[i][j] = fmaf(a2[i], b4[j], acc[i][j]);
        }
        __syncthreads();
    }

    // Gate epilogue: unit = n0/4 + tx; rows = batch m0 + ty*2 + i
    const int u = (n0 >> 2) + tx;
    const float* bI = biasI + dir * 2048 + u * 4;
    const float b0 = bI[0], b1 = bI[1], b2 = bI[2], b3 = bI[3];
    #pragma unroll
    for (int i = 0; i < 2; ++i) {
        const int brow = m0 + ty * 2 + i;
        const float zi = acc[i][0] + b0;
        const float zf = acc[i][1] + b1;
        const float zg = acc[i][2] + b2;
        const float zo = acc[i][3] + b3;
        float* cp = cbuf + ((long)dir * BB + brow) * HH + u;
        float c = (step > 0) ? *cp : 0.0f;
        c = sigm9(zf) * c + sigm9(zi) * tanhf(zg);
        *cp = c;
        hs[((long)brow * SS + s_eff) * H2 + dir * HH + u] = sigm9(zo) * tanhf(c);
    }
}

// ---------------------------------------------------------------------------
// Generic fp32 tiled GEMM (validated). BT=1: B as [N][K]; BT=0: B as [K][N].
// ACT=1: tanh epilogue.
// ---------------------------------------------------------------------------
template<int BT, int ACT>
__global__ __launch_bounds__(256) void k_gemm9(
    const float* __restrict__ A, long lda, long sAz,
    const float* __restrict__ Bm, long ldb, long sBz,
    float* __restrict__ Cf, long ldc, long sCz, int N, int K)
{
    __shared__ float As[16][68];
    __shared__ float Bs[16][68];
    const int n0 = blockIdx.x * 64;
    const int m0 = blockIdx.y * 64;
    const float* Ab = A + (long)blockIdx.z * sAz;
    const float* Bb = Bm + (long)blockIdx.z * sBz;
    const int tid = threadIdx.x;
    const int ty = tid >> 4, tx = tid & 15;
    float acc[4][4] = {};

    for (int k0 = 0; k0 < K; k0 += 16) {
        {
            const int i = tid >> 2, kk = (tid & 3) * 4;
            const float4 v = *(const float4*)(Ab + (long)(m0 + i) * lda + k0 + kk);
            As[kk][i] = v.x; As[kk + 1][i] = v.y; As[kk + 2][i] = v.z; As[kk + 3][i] = v.w;
        }
        if (BT) {
            const int j = tid >> 2, kk = (tid & 3) * 4;
            const int n = n0 + j;
            float4 v = make_float4(0.f, 0.f, 0.f, 0.f);
            if (n < N) v = *(const float4*)(Bb + (long)n * ldb + k0 + kk);
            Bs[kk][j] = v.x; Bs[kk + 1][j] = v.y; Bs[kk + 2][j] = v.z; Bs[kk + 3][j] = v.w;
        } else {
            const int kk = tid >> 4, jj = (tid & 15) * 4;
            const int n = n0 + jj;
            float4 v = make_float4(0.f, 0.f, 0.f, 0.f);
            if (n + 3 < N) {
                v = *(const float4*)(Bb + (long)(k0 + kk) * ldb + n);
            } else {
                const float* src = Bb + (long)(k0 + kk) * ldb + n;
                if (n < N)     v.x = src[0];
                if (n + 1 < N) v.y = src[1];
                if (n + 2 < N) v.z = src[2];
            }
            *(float4*)&Bs[kk][jj] = v;
        }
        __syncthreads();
        #pragma unroll
        for (int k = 0; k < 16; ++k) {
            const float4 av = *(const float4*)&As[k][ty * 4];
            const float4 bv = *(const float4*)&Bs[k][tx * 4];
            const float a4[4] = {av.x, av.y, av.z, av.w};
            const float b4[4] = {bv.x, bv.y, bv.z, bv.w};
            #pragma unroll
            for (int i = 0; i < 4; ++i)
                #pragma unroll
                for (int j = 0; j < 4; ++j)
                    acc[i][j] = fmaf(a4[i], b4[j], acc[i][j]);
        }
        __syncthreads();
    }

    const long zc = (long)blockIdx.z * sCz;
    #pragma unroll
    for (int i = 0; i < 4; ++i) {
        const int m = m0 + ty * 4 + i;
        #pragma unroll
        for (int j = 0; j < 4; ++j) {
            const int n = n0 + tx * 4 + j;
            if (n < N) {
                float val = acc[i][j];
                if (ACT == 1) val = tanhf(val);
                Cf[zc + (long)m * ldc + n] = val;
            }
        }
    }
}

// attlog[b,r,s] = sum_a pre[b,s,a] * ws2[r,a]
__global__ __launch_bounds__(256) void attlog9(
    const float* __restrict__ pre, const float* __restrict__ ws2,
    float* __restrict__ attlog)
{
    const int idx = blockIdx.x * 256 + threadIdx.x;
    if (idx >= BB * RR * SS) return;
    const int s = idx & 63, r = (idx >> 6) & 7, b = idx >> 9;
    const float* p = pre + ((long)b * SS + s) * DA;
    const float* w = ws2 + (long)r * DA;
    float acc = 0.0f;
    for (int a = 0; a < DA; ++a) acc = fmaf(p[a], w[a], acc);
    attlog[idx] = acc;
}

// softmax over s per (b,r)
__global__ __launch_bounds__(256) void soft9(
    const float* __restrict__ attlog, float* __restrict__ att_out)
{
    const int idx = blockIdx.x * 256 + threadIdx.x;
    if (idx >= BB * RR) return;
    const float* L = attlog + (long)idx * SS;
    float mx = L[0];
    for (int s = 1; s < SS; ++s) mx = fmaxf(mx, L[s]);
    float sm = 0.0f;
    for (int s = 0; s < SS; ++s) sm += expf(L[s] - mx);
    for (int s = 0; s < SS; ++s)
        att_out[(long)idx * SS + s] = expf(L[s] - mx) / sm;
}

// sem[b,r,d] = sum_s att[b,r,s] * hs[b][s][d]
__global__ __launch_bounds__(256) void sem9(
    const float* __restrict__ att, const float* __restrict__ hs,
    float* __restrict__ sem)
{
    const long idx = (long)blockIdx.x * 256 + threadIdx.x;
    if (idx >= (long)BB * RR * H2) return;
    const int d = (int)(idx & 1023);
    const int r = (int)((idx >> 10) & 7);
    const int b = (int)(idx >> 13);
    const float* aw = att + ((long)b * RR + r) * SS;
    float acc = 0.0f;
    for (int s = 0; s < SS; ++s)
        acc = fmaf(aw[s], hs[((long)b * SS + s) * H2 + d], acc);
    sem[idx] = acc;
}

// ---------------------------------------------------------------------------
// Dynamic routing
// ---------------------------------------------------------------------------
__global__ __launch_bounds__(256) void route9(
    const float* __restrict__ pred,
    float* __restrict__ cls_out, float* __restrict__ routes_out)
{
    __shared__ float predS[RR * CP];
    __shared__ float logitS[RR * CC];
    __shared__ float routeS[RR * CC];
    __shared__ float preactS[CP];
    __shared__ float vS[CP];
    __shared__ float scaleS[CC];
    __shared__ float rmax[RR], rsum[RR];
    const int b = blockIdx.x, tid = threadIdx.x;
    const float* ps = pred + (long)b * RR * CP;
    for (int i = tid; i < RR * CP; i += 256) predS[i] = ps[i];
    for (int i = tid; i < RR * CC; i += 256) logitS[i] = 0.0f;
    __syncthreads();

    for (int it = 0; it < 3; ++it) {
        if (tid < RR) {
            float mx = -1e30f;
            for (int c = 0; c < CC; ++c) mx = fmaxf(mx, logitS[tid * CC + c]);
            float sm = 0.0f;
            for (int c = 0; c < CC; ++c) sm += expf(logitS[tid * CC + c] - mx);
            rmax[tid] = mx; rsum[tid] = sm;
        }
        __syncthreads();
        for (int i = tid; i < RR * CC; i += 256) {
            const int r = i / CC;
            routeS[i] = expf(logitS[i] - rmax[r]) / rsum[r];
        }
        __syncthreads();
        for (int cp = tid; cp < CP; cp += 256) {
            const int c = cp >> 4;
            float a = 0.0f;
            #pragma unroll
            for (int r = 0; r < RR; ++r)
                a = fmaf(routeS[r * CC + c], predS[r * CP + cp], a);
            preactS[cp] = a;
        }
        __syncthreads();
        for (int c = tid; c < CC; c += 256) {
            float n2 = 0.0f;
            #pragma unroll
            for (int p = 0; p < PP; ++p) { const float x = preactS[c * PP + p]; n2 = fmaf(x, x, n2); }
            scaleS[c] = (n2 / (1.0f + n2)) / sqrtf(n2 + 1e-9f);
        }
        __syncthreads();
        for (int cp = tid; cp < CP; cp += 256) vS[cp] = preactS[cp] * scaleS[cp >> 4];
        __syncthreads();
        for (int i = tid; i < RR * CC; i += 256) {
            const int r = i / CC, c = i % CC;
            float a = 0.0f;
            #pragma unroll
            for (int p = 0; p < PP; ++p)
                a = fmaf(predS[r * CP + c * PP + p], vS[c * PP + p], a);
            logitS[i] += a;
        }
        __syncthreads();
    }

    for (int i = tid; i < RR * CC; i += 256)
        routes_out[(long)b * RR * CC + i] = routeS[i];
    for (int c = tid; c < CC; c += 256) {
        float n2 = 0.0f;
        #pragma unroll
        for (int p = 0; p < PP; ++p) { const float x = vS[c * PP + p]; n2 = fmaf(x, x, n2); }
        cls_out[(long)b * CC + c] = sqrtf(n2);
    }
}

// ---------------------------------------------------------------------------
extern "C" void kernel_launch(void* const* d_in, const int* in_sizes, int n_in,
                              void* d_out, int out_size, void* d_ws, size_t ws_size,
                              hipStream_t stream)
{
    (void)in_sizes; (void)n_in; (void)out_size;
    const int*   ids   = (const int*)d_in[0];
    const float* emb   = (const float*)d_in[2];
    const float* wih_f = (const float*)d_in[3];
    const float* whh_f = (const float*)d_in[4];
    const float* bih_f = (const float*)d_in[5];
    const float* bhh_f = (const float*)d_in[6];
    const float* wih_b = (const float*)d_in[7];
    const float* whh_b = (const float*)d_in[8];
    const float* bih_b = (const float*)d_in[9];
    const float* bhh_b = (const float*)d_in[10];
    const float* ws1   = (const float*)d_in[11];
    const float* ws2   = (const float*)d_in[12];
    const float* caps  = (const float*)d_in[13];
    float* out = (float*)d_out;   // fp32 outputs

    // Workspace: hs | cbuf | region1 (X,WpI,biasI -> pre,sem) | attlog
    float* ws   = (float*)d_ws;
    float* hs   = ws;                         // [256][64][1024] = 16,777,216
    float* cbuf = hs + 16777216;              // [2][256][512]   =    262,144
    float* region1 = cbuf + 262144;           // 8,327,168
    float* X     = region1;                   // [64][256][304]  =  4,980,736
    float* WpI   = region1 + 4980736;         // [2][2048][816]  =  3,342,336
    float* biasI = region1 + 8323072;         // [2][2048]       =      4,096
    float* pre   = region1;                   // [256][64][350]  =  5,734,400 (after LSTM)
    float* sem   = region1 + 5734400;         // [256][8][1024]  =  2,097,152
    float* attlog = region1 + 8327168;        //    131,072
    const size_t need = (size_t)(16777216 + 262144 + 8327168 + 131072) * 4;
    if (ws_size < need) return;

    // Stage inputs
    k_gather9<<<(int)(((long)SS * BB * EP + 255) / 256), 256, 0, stream>>>(ids, emb, X);
    k_packw9<<<(int)(((long)2 * 2048 * KK9 + 255) / 256), 256, 0, stream>>>(
        wih_f, whh_f, wih_b, whh_b, WpI);
    k_packb9<<<16, 256, 0, stream>>>(bih_f, bhh_f, bih_b, bhh_b, biasI);

    // Bidirectional LSTM: one fused kernel per step, 512 blocks (2/CU)
    for (int step = 0; step < SS; ++step)
        k_lstm_step9<<<dim3(32, 8, 2), 256, 0, stream>>>(X, hs, WpI, biasI, cbuf, step);

    // pre = tanh(hs @ ws1^T)  [M=16384, N=350, K=1024]
    {
        dim3 g((DA + 63) / 64, (BB * SS) / 64, 1);
        k_gemm9<1, 1><<<g, 256, 0, stream>>>(hs, H2, 0, ws1, H2, 0,
                                             pre, DA, 0, DA, H2);
    }

    attlog9<<<512, 256, 0, stream>>>(pre, ws2, attlog);
    soft9<<<8, 256, 0, stream>>>(attlog, out + ATT_OFF);
    sem9<<<8192, 256, 0, stream>>>(out + ATT_OFF, hs, sem);

    // pred[b,r,:] = sem[b,r,:] @ caps[r]  [M=256, N=2400, K=1024] x8 (z=r)
    {
        dim3 g((CP + 63) / 64, BB / 64, RR);
        k_gemm9<0, 0><<<g, 256, 0, stream>>>(sem, (long)RR * H2, H2,
                                             caps, CP, (long)H2 * CP,
                                             out + PRED_OFF, (long)RR * CP, CP, CP, H2);
    }

    route9<<<BB, 256, 0, stream>>>(out + PRED_OFF, out + CL_OFF, out + ROUTES_OFF);
}

// Round 10
// 2024.798 us; speedup vs baseline: 1.7519x; 1.5086x over previous
//
#include <hip/hip_runtime.h>
#include <hip/hip_bf16.h>
#include <math.h>

// Sizes
#define BB 256
#define SS 64
#define EE 300
#define EPX 320   // X padded to 320 (10 k-tiles of 32)
#define KP 832    // total K = 320 + 512
#define KAP 840   // LDS A row stride (f16) — bank-friendly pad
#define VV 30000
#define HH 512
#define H2 1024
#define DA 350
#define RR 8
#define CC 150
#define PP 16
#define CP 2400

// Output layout (elements, fp32)
#define ATT_OFF    0L
#define CL_OFF     131072L
#define PRED_OFF   169472L
#define ROUTES_OFF 5084672L

typedef _Float16 f16;
typedef f16  f16x8 __attribute__((ext_vector_type(8)));
typedef float f32x4 __attribute__((ext_vector_type(4)));

static __device__ __forceinline__ float sigmA(float x) { return 1.0f / (1.0f + expf(-x)); }

// ---------------------------------------------------------------------------
// X16[s][b][320] = fp16(embedding[ids[b][s]]), zero pad 300..319
// ---------------------------------------------------------------------------
__global__ __launch_bounds__(256) void k_gather16(
    const int* __restrict__ ids, const float* __restrict__ emb, f16* __restrict__ X16)
{
    const long idx = (long)blockIdx.x * 256 + threadIdx.x;
    if (idx >= (long)SS * BB * EPX) return;
    const int e = (int)(idx % EPX);
    const int row = (int)(idx / EPX);
    const int s = row >> 8, b = row & 255;
    int tok = ids[(long)b * SS + s];
    if ((unsigned)tok >= (unsigned)VV) tok = 0;
    X16[idx] = (e < EE) ? (f16)emb[(long)tok * EE + e] : (f16)0.0f;
}

// W16[dir][j][k] fp16, j = gate*512+unit (native row order):
//   k<300: wih[j][k]; 300..319: 0; 320..831: whh[j][k-320]
__global__ __launch_bounds__(256) void k_packw16(
    const float* __restrict__ wihF, const float* __restrict__ whhF,
    const float* __restrict__ wihB, const float* __restrict__ whhB,
    f16* __restrict__ W16)
{
    const long idx = (long)blockIdx.x * 256 + threadIdx.x;
    if (idx >= (long)2 * 2048 * KP) return;
    const int dir = (int)(idx / (2048 * KP));
    const int rem = (int)(idx % (2048 * KP));
    const int j = rem / KP, k = rem % KP;
    const float* wih = dir ? wihB : wihF;
    const float* whh = dir ? whhB : whhF;
    float v;
    if (k < EE)        v = wih[(long)j * EE + k];
    else if (k < EPX)  v = 0.0f;
    else               v = whh[(long)j * HH + (k - EPX)];
    W16[idx] = (f16)v;
}

// ---------------------------------------------------------------------------
// fp16 MFMA LSTM step. Block = 64 batches x 64 units (4 waves; wave w owns
// units u0b + w*16). Each wave: 4 b-tiles x 4 gate-quadrant accumulators.
// K = 832 (X 0..319 | h_prev 320..831). A staged in LDS; B direct from L2.
// Epilogue: lane holds (i,f,g,o) of (b,u) in regs -> c/h update in-register.
// hbuf double-buffered across steps (hr = h_{s-1}, hw = h_s).
// ---------------------------------------------------------------------------
__global__ __launch_bounds__(256) void k_step16(
    const f16* __restrict__ X16, const f16* __restrict__ W16,
    const f16* __restrict__ hr, f16* __restrict__ hw,
    float* __restrict__ cbuf, float* __restrict__ hs,
    const float* __restrict__ bihF, const float* __restrict__ bhhF,
    const float* __restrict__ bihB, const float* __restrict__ bhhB,
    int step)
{
    __shared__ f16 Al[64 * KAP];   // 105 KB
    const int dir = blockIdx.z;
    const int b0  = blockIdx.x * 64;
    const int u0b = blockIdx.y * 64;
    const int s_eff = dir ? (SS - 1 - step) : step;
    const int tid = threadIdx.x;
    const int wave = tid >> 6, lane = tid & 63;

    // stage A: X part (k 0..319), 64 rows x 160 words
    {
        const uint* Xw = (const uint*)(X16 + ((long)s_eff * BB + b0) * EPX);
        uint* Aw = (uint*)Al;
        for (int i = tid; i < 64 * 160; i += 256) {
            const int r = i / 160, w = i - r * 160;
            Aw[r * (KAP / 2) + w] = Xw[r * 160 + w];
        }
    }
    // stage A: h_prev part (k 320..831), 64 rows x 256 words
    if (step > 0) {
        const uint* Hw = (const uint*)(hr + ((long)dir * BB + b0) * HH);
        uint* Aw = (uint*)Al;
        for (int i = tid; i < 64 * 256; i += 256) {
            const int r = i >> 8, w = i & 255;
            Aw[r * (KAP / 2) + 160 + w] = Hw[r * 256 + w];
        }
    }
    __syncthreads();

    const int l15  = lane & 15;
    const int kgrp = (lane >> 4) * 8;
    const int u    = u0b + (wave << 4) + l15;

    f32x4 acc[4][4];   // [b-tile][gate]
    #pragma unroll
    for (int bt = 0; bt < 4; ++bt)
        #pragma unroll
        for (int g = 0; g < 4; ++g) acc[bt][g] = (f32x4){0.f, 0.f, 0.f, 0.f};

    const f16* Wd = W16 + (long)dir * 2048 * KP;
    const int nkt = step ? 26 : 10;
    #pragma unroll 2
    for (int kt = 0; kt < nkt; ++kt) {
        const int k0 = kt * 32 + kgrp;
        f16x8 bfr[4];
        #pragma unroll
        for (int g = 0; g < 4; ++g)
            bfr[g] = *(const f16x8*)(Wd + (long)(g * HH + u) * KP + k0);
        #pragma unroll
        for (int bt = 0; bt < 4; ++bt) {
            const f16x8 afr = *(const f16x8*)(Al + (bt * 16 + l15) * KAP + k0);
            #pragma unroll
            for (int g = 0; g < 4; ++g)
                acc[bt][g] = __builtin_amdgcn_mfma_f32_16x16x32_f16(
                    afr, bfr[g], acc[bt][g], 0, 0, 0);
        }
    }

    // gate epilogue
    const float* bi = dir ? bihB : bihF;
    const float* bh = dir ? bhhB : bhhF;
    const float bias0 = bi[u]           + bh[u];
    const float bias1 = bi[HH + u]      + bh[HH + u];
    const float bias2 = bi[2 * HH + u]  + bh[2 * HH + u];
    const float bias3 = bi[3 * HH + u]  + bh[3 * HH + u];
    const int rbase = (lane >> 4) * 4;
    #pragma unroll
    for (int bt = 0; bt < 4; ++bt) {
        #pragma unroll
        for (int i = 0; i < 4; ++i) {
            const int b = b0 + bt * 16 + rbase + i;
            const float zi = acc[bt][0][i] + bias0;
            const float zf = acc[bt][1][i] + bias1;
            const float zg = acc[bt][2][i] + bias2;
            const float zo = acc[bt][3][i] + bias3;
            float* cp = cbuf + ((long)dir * BB + b) * HH + u;
            float c = step ? *cp : 0.0f;
            c = sigmA(zf) * c + sigmA(zi) * tanhf(zg);
            *cp = c;
            const float h = sigmA(zo) * tanhf(c);
            hs[((long)b * SS + s_eff) * H2 + dir * HH + u] = h;
            hw[((long)dir * BB + b) * HH + u] = (f16)h;
        }
    }
}

// ---------------------------------------------------------------------------
// Generic fp32 tiled GEMM (validated). BT=1: B as [N][K]; BT=0: B as [K][N].
// ACT=1: tanh epilogue.
// ---------------------------------------------------------------------------
template<int BT, int ACT>
__global__ __launch_bounds__(256) void k_gemmA(
    const float* __restrict__ A, long lda, long sAz,
    const float* __restrict__ Bm, long ldb, long sBz,
    float* __restrict__ Cf, long ldc, long sCz, int N, int K)
{
    __shared__ float As[16][68];
    __shared__ float Bs[16][68];
    const int n0 = blockIdx.x * 64;
    const int m0 = blockIdx.y * 64;
    const float* Ab = A + (long)blockIdx.z * sAz;
    const float* Bb = Bm + (long)blockIdx.z * sBz;
    const int tid = threadIdx.x;
    const int ty = tid >> 4, tx = tid & 15;
    float acc[4][4] = {};

    for (int k0 = 0; k0 < K; k0 += 16) {
        {
            const int i = tid >> 2, kk = (tid & 3) * 4;
            const float4 v = *(const float4*)(Ab + (long)(m0 + i) * lda + k0 + kk);
            As[kk][i] = v.x; As[kk + 1][i] = v.y; As[kk + 2][i] = v.z; As[kk + 3][i] = v.w;
        }
        if (BT) {
            const int j = tid >> 2, kk = (tid & 3) * 4;
            const int n = n0 + j;
            float4 v = make_float4(0.f, 0.f, 0.f, 0.f);
            if (n < N) v = *(const float4*)(Bb + (long)n * ldb + k0 + kk);
            Bs[kk][j] = v.x; Bs[kk + 1][j] = v.y; Bs[kk + 2][j] = v.z; Bs[kk + 3][j] = v.w;
        } else {
            const int kk = tid >> 4, jj = (tid & 15) * 4;
            const int n = n0 + jj;
            float4 v = make_float4(0.f, 0.f, 0.f, 0.f);
            if (n + 3 < N) {
                v = *(const float4*)(Bb + (long)(k0 + kk) * ldb + n);
            } else {
                const float* src = Bb + (long)(k0 + kk) * ldb + n;
                if (n < N)     v.x = src[0];
                if (n + 1 < N) v.y = src[1];
                if (n + 2 < N) v.z = src[2];
            }
            *(float4*)&Bs[kk][jj] = v;
        }
        __syncthreads();
        #pragma unroll
        for (int k = 0; k < 16; ++k) {
            const float4 av = *(const float4*)&As[k][ty * 4];
            const float4 bv = *(const float4*)&Bs[k][tx * 4];
            const float a4[4] = {av.x, av.y, av.z, av.w};
            const float b4[4] = {bv.x, bv.y, bv.z, bv.w};
            #pragma unroll
            for (int i = 0; i < 4; ++i)
                #pragma unroll
                for (int j = 0; j < 4; ++j)
                    acc[i][j] = fmaf(a4[i], b4[j], acc[i][j]);
        }
        __syncthreads();
    }

    const long zc = (long)blockIdx.z * sCz;
    #pragma unroll
    for (int i = 0; i < 4; ++i) {
        const int m = m0 + ty * 4 + i;
        #pragma unroll
        for (int j = 0; j < 4; ++j) {
            const int n = n0 + tx * 4 + j;
            if (n < N) {
                float val = acc[i][j];
                if (ACT == 1) val = tanhf(val);
                Cf[zc + (long)m * ldc + n] = val;
            }
        }
    }
}

// attlog[b,r,s] = sum_a pre[b,s,a] * ws2[r,a]
__global__ __launch_bounds__(256) void attlogA(
    const float* __restrict__ pre, const float* __restrict__ ws2,
    float* __restrict__ attlog)
{
    const int idx = blockIdx.x * 256 + threadIdx.x;
    if (idx >= BB * RR * SS) return;
    const int s = idx & 63, r = (idx >> 6) & 7, b = idx >> 9;
    const float* p = pre + ((long)b * SS + s) * DA;
    const float* w = ws2 + (long)r * DA;
    float acc = 0.0f;
    for (int a = 0; a < DA; ++a) acc = fmaf(p[a], w[a], acc);
    attlog[idx] = acc;
}

// softmax over s per (b,r)
__global__ __launch_bounds__(256) void softA(
    const float* __restrict__ attlog, float* __restrict__ att_out)
{
    const int idx = blockIdx.x * 256 + threadIdx.x;
    if (idx >= BB * RR) return;
    const float* L = attlog + (long)idx * SS;
    float mx = L[0];
    for (int s = 1; s < SS; ++s) mx = fmaxf(mx, L[s]);
    float sm = 0.0f;
    for (int s = 0; s < SS; ++s) sm += expf(L[s] - mx);
    for (int s = 0; s < SS; ++s)
        att_out[(long)idx * SS + s] = expf(L[s] - mx) / sm;
}

// sem[b,r,d] = sum_s att[b,r,s] * hs[b][s][d]
__global__ __launch_bounds__(256) void semA(
    const float* __restrict__ att, const float* __restrict__ hs,
    float* __restrict__ sem)
{
    const long idx = (long)blockIdx.x * 256 + threadIdx.x;
    if (idx >= (long)BB * RR * H2) return;
    const int d = (int)(idx & 1023);
    const int r = (int)((idx >> 10) & 7);
    const int b = (int)(idx >> 13);
    const float* aw = att + ((long)b * RR + r) * SS;
    float acc = 0.0f;
    for (int s = 0; s < SS; ++s)
        acc = fmaf(aw[s], hs[((long)b * SS + s) * H2 + d], acc);
    sem[idx] = acc;
}

// ---------------------------------------------------------------------------
// Dynamic routing
// ---------------------------------------------------------------------------
__global__ __launch_bounds__(256) void routeA(
    const float* __restrict__ pred,
    float* __restrict__ cls_out, float* __restrict__ routes_out)
{
    __shared__ float predS[RR * CP];
    __shared__ float logitS[RR * CC];
    __shared__ float routeS[RR * CC];
    __shared__ float preactS[CP];
    __shared__ float vS[CP];
    __shared__ float scaleS[CC];
    __shared__ float rmax[RR], rsum[RR];
    const int b = blockIdx.x, tid = threadIdx.x;
    const float* ps = pred + (long)b * RR * CP;
    for (int i = tid; i < RR * CP; i += 256) predS[i] = ps[i];
    for (int i = tid; i < RR * CC; i += 256) logitS[i] = 0.0f;
    __syncthreads();

    for (int it = 0; it < 3; ++it) {
        if (tid < RR) {
            float mx = -1e30f;
            for (int c = 0; c < CC; ++c) mx = fmaxf(mx, logitS[tid * CC + c]);
            float sm = 0.0f;
            for (int c = 0; c < CC; ++c) sm += expf(logitS[tid * CC + c] - mx);
            rmax[tid] = mx; rsum[tid] = sm;
        }
        __syncthreads();
        for (int i = tid; i < RR * CC; i += 256) {
            const int r = i / CC;
            routeS[i] = expf(logitS[i] - rmax[r]) / rsum[r];
        }
        __syncthreads();
        for (int cp = tid; cp < CP; cp += 256) {
            const int c = cp >> 4;
            float a = 0.0f;
            #pragma unroll
            for (int r = 0; r < RR; ++r)
                a = fmaf(routeS[r * CC + c], predS[r * CP + cp], a);
            preactS[cp] = a;
        }
        __syncthreads();
        for (int c = tid; c < CC; c += 256) {
            float n2 = 0.0f;
            #pragma unroll
            for (int p = 0; p < PP; ++p) { const float x = preactS[c * PP + p]; n2 = fmaf(x, x, n2); }
            scaleS[c] = (n2 / (1.0f + n2)) / sqrtf(n2 + 1e-9f);
        }
        __syncthreads();
        for (int cp = tid; cp < CP; cp += 256) vS[cp] = preactS[cp] * scaleS[cp >> 4];
        __syncthreads();
        for (int i = tid; i < RR * CC; i += 256) {
            const int r = i / CC, c = i % CC;
            float a = 0.0f;
            #pragma unroll
            for (int p = 0; p < PP; ++p)
                a = fmaf(predS[r * CP + c * PP + p], vS[c * PP + p], a);
            logitS[i] += a;
        }
        __syncthreads();
    }

    for (int i = tid; i < RR * CC; i += 256)
        routes_out[(long)b * RR * CC + i] = routeS[i];
    for (int c = tid; c < CC; c += 256) {
        float n2 = 0.0f;
        #pragma unroll
        for (int p = 0; p < PP; ++p) { const float x = vS[c * PP + p]; n2 = fmaf(x, x, n2); }
        cls_out[(long)b * CC + c] = sqrtf(n2);
    }
}

// ---------------------------------------------------------------------------
extern "C" void kernel_launch(void* const* d_in, const int* in_sizes, int n_in,
                              void* d_out, int out_size, void* d_ws, size_t ws_size,
                              hipStream_t stream)
{
    (void)in_sizes; (void)n_in; (void)out_size;
    const int*   ids   = (const int*)d_in[0];
    const float* emb   = (const float*)d_in[2];
    const float* wih_f = (const float*)d_in[3];
    const float* whh_f = (const float*)d_in[4];
    const float* bih_f = (const float*)d_in[5];
    const float* bhh_f = (const float*)d_in[6];
    const float* wih_b = (const float*)d_in[7];
    const float* whh_b = (const float*)d_in[8];
    const float* bih_b = (const float*)d_in[9];
    const float* bhh_b = (const float*)d_in[10];
    const float* ws1   = (const float*)d_in[11];
    const float* ws2   = (const float*)d_in[12];
    const float* caps  = (const float*)d_in[13];
    float* out = (float*)d_out;   // fp32 outputs

    // Workspace (floats)
    float* ws   = (float*)d_ws;
    float* hs   = ws;                          // 16,777,216
    float* cbuf = hs + 16777216;               //    262,144
    f16*  X16   = (f16*)(cbuf + 262144);       // 5,242,880 f16 (2,621,440 f32)
    f16*  W16   = X16 + 5242880;               // 3,407,872 f16 (1,703,936 f32)
    f16*  hb0   = W16 + 3407872;               //   262,144 f16 (131,072 f32)
    f16*  hb1   = hb0 + 262144;                //   262,144 f16 (131,072 f32)
    float* pre  = (float*)(hb1 + 262144);      //  5,734,400
    float* sem  = pre + 5734400;               //  2,097,152
    float* attlog = sem + 2097152;             //    131,072
    const size_t need = (size_t)(16777216 + 262144 + 2621440 + 1703936
                                 + 131072 + 131072 + 5734400 + 2097152 + 131072) * 4;
    if (ws_size < need) return;

    // Stage fp16 inputs
    k_gather16<<<(int)(((long)SS * BB * EPX + 255) / 256), 256, 0, stream>>>(ids, emb, X16);
    k_packw16<<<(int)(((long)2 * 2048 * KP + 255) / 256), 256, 0, stream>>>(
        wih_f, whh_f, wih_b, whh_b, W16);

    // Bidirectional LSTM: fp16 MFMA step kernels, h double-buffered
    for (int step = 0; step < SS; ++step) {
        f16* hrd = (step & 1) ? hb1 : hb0;
        f16* hwr = (step & 1) ? hb0 : hb1;
        k_step16<<<dim3(4, 8, 2), 256, 0, stream>>>(
            X16, W16, hrd, hwr, cbuf, hs, bih_f, bhh_f, bih_b, bhh_b, step);
    }

    // pre = tanh(hs @ ws1^T)  [M=16384, N=350, K=1024]
    {
        dim3 g((DA + 63) / 64, (BB * SS) / 64, 1);
        k_gemmA<1, 1><<<g, 256, 0, stream>>>(hs, H2, 0, ws1, H2, 0,
                                             pre, DA, 0, DA, H2);
    }

    attlogA<<<512, 256, 0, stream>>>(pre, ws2, attlog);
    softA<<<8, 256, 0, stream>>>(attlog, out + ATT_OFF);
    semA<<<8192, 256, 0, stream>>>(out + ATT_OFF, hs, sem);

    // pred[b,r,:] = sem[b,r,:] @ caps[r]  [M=256, N=2400, K=1024] x8 (z=r)
    {
        dim3 g((CP + 63) / 64, BB / 64, RR);
        k_gemmA<0, 0><<<g, 256, 0, stream>>>(sem, (long)RR * H2, H2,
                                             caps, CP, (long)H2 * CP,
                                             out + PRED_OFF, (long)RR * CP, CP, CP, H2);
    }

    routeA<<<BB, 256, 0, stream>>>(out + PRED_OFF, out + CL_OFF, out + ROUTES_OFF);
}

// Round 11
// 1548.060 us; speedup vs baseline: 2.2915x; 1.3080x over previous
//
#include <hip/hip_runtime.h>
#include <hip/hip_bf16.h>
#include <math.h>

// Sizes
#define BB 256
#define SS 64
#define EE 300
#define EPX 320   // X padded
#define KP 832    // 320 + 512
#define VV 30000
#define HH 512
#define H2 1024
#define DA 350
#define RR 8
#define CC 150
#define PP 16
#define CP 2400

// Output layout (elements, fp32)
#define ATT_OFF    0L
#define CL_OFF     131072L
#define PRED_OFF   169472L
#define ROUTES_OFF 5084672L

typedef _Float16 f16;
typedef f16  f16x8 __attribute__((ext_vector_type(8)));
typedef float f32x4 __attribute__((ext_vector_type(4)));

static __device__ __forceinline__ float sigmB(float x) { return 1.0f / (1.0f + expf(-x)); }

// ---------------------------------------------------------------------------
// X16[s][b][320] = f16(emb[ids[b][s]]), pad 300..319 = 0
// ---------------------------------------------------------------------------
__global__ __launch_bounds__(256) void b_gather(
    const int* __restrict__ ids, const float* __restrict__ emb, f16* __restrict__ X16)
{
    const long idx = (long)blockIdx.x * 256 + threadIdx.x;
    if (idx >= (long)SS * BB * EPX) return;
    const int e = (int)(idx % EPX);
    const int row = (int)(idx / EPX);
    const int s = row >> 8, b = row & 255;
    int tok = ids[(long)b * SS + s];
    if ((unsigned)tok >= (unsigned)VV) tok = 0;
    X16[idx] = (e < EE) ? (f16)emb[(long)tok * EE + e] : (f16)0.0f;
}

// W16[dir][j][832], j = gate*512+unit: k<300 wih, <320 zero, else whh
__global__ __launch_bounds__(256) void b_packw(
    const float* __restrict__ wihF, const float* __restrict__ whhF,
    const float* __restrict__ wihB, const float* __restrict__ whhB,
    f16* __restrict__ W16)
{
    const long idx = (long)blockIdx.x * 256 + threadIdx.x;
    if (idx >= (long)2 * 2048 * KP) return;
    const int dir = (int)(idx / (2048 * KP));
    const int rem = (int)(idx % (2048 * KP));
    const int j = rem / KP, k = rem % KP;
    const float* wih = dir ? wihB : wihF;
    const float* whh = dir ? whhB : whhF;
    float v;
    if (k < EE)        v = wih[(long)j * EE + k];
    else if (k < EPX)  v = 0.0f;
    else               v = whh[(long)j * HH + (k - EPX)];
    W16[idx] = (f16)v;
}

// ws1_16[384][1024], rows >= 350 zero
__global__ __launch_bounds__(256) void b_packws1(
    const float* __restrict__ ws1, f16* __restrict__ w)
{
    const int idx = blockIdx.x * 256 + threadIdx.x;
    if (idx >= 384 * 1024) return;
    const int j = idx >> 10;
    w[idx] = (j < DA) ? (f16)ws1[idx] : (f16)0.0f;
}

// capsT16[r][2432][1024] = caps[r][k][n] transposed; rows >= 2400 zero.
// LDS-tiled 32x32. grid (32 kt, 76 nt, 8 r), 256 thr.
__global__ __launch_bounds__(256) void b_packcapsT(
    const float* __restrict__ caps, f16* __restrict__ capsT)
{
    __shared__ float t[32][33];
    const int r = blockIdx.z, k0 = blockIdx.x * 32, n0 = blockIdx.y * 32;
    const int tx = threadIdx.x & 31, ty = threadIdx.x >> 5;
    #pragma unroll
    for (int p = 0; p < 4; ++p) {
        const int k = k0 + ty + p * 8;
        const int n = n0 + tx;
        t[ty + p * 8][tx] = (n < CP) ? caps[((long)r * H2 + k) * CP + n] : 0.0f;
    }
    __syncthreads();
    #pragma unroll
    for (int p = 0; p < 4; ++p) {
        const int n = n0 + ty + p * 8;
        if (n < 2432)
            capsT[((long)r * 2432 + n) * H2 + k0 + tx] = (f16)t[tx][ty + p * 8];
    }
}

// ---------------------------------------------------------------------------
// LSTM step, fp16 MFMA, 256 blocks (32b x 32u x 2dir). No LDS; direct loads.
// Wave w: b-tile = w>>1, u-tile = w&1. acc[4] = 4 gates of one 16x16 tile.
// h state carried in hs16[b][s][1024] (f16); race-free across (dir,s) slices.
// ---------------------------------------------------------------------------
__global__ __launch_bounds__(256, 1) void b_step(
    const f16* __restrict__ X16, f16* __restrict__ hs16,
    const f16* __restrict__ W16, float* __restrict__ cbuf,
    const float* __restrict__ bihF, const float* __restrict__ bhhF,
    const float* __restrict__ bihB, const float* __restrict__ bhhB,
    int step)
{
    const int dir = blockIdx.z;
    const int b0  = blockIdx.x * 32;
    const int u0  = blockIdx.y * 32;
    const int s_eff  = dir ? (SS - 1 - step) : step;
    const int s_prev = dir ? (s_eff + 1) : (s_eff - 1);
    const int tid = threadIdx.x;
    const int wave = tid >> 6, lane = tid & 63;
    const int bt = wave >> 1, ut = wave & 1;
    const int l15 = lane & 15;
    const int kgrp = (lane >> 4) * 8;
    const int arow = b0 + bt * 16 + l15;
    const int u = u0 + ut * 16 + l15;

    f32x4 acc[4];
    #pragma unroll
    for (int g = 0; g < 4; ++g) acc[g] = (f32x4){0.f, 0.f, 0.f, 0.f};

    const f16* Wd = W16 + (long)dir * 2048 * KP;
    // X part: kt 0..9
    {
        const f16* Xrow = X16 + ((long)s_eff * BB + arow) * EPX;
        #pragma unroll
        for (int kt = 0; kt < 10; ++kt) {
            const int k0 = kt * 32 + kgrp;
            const f16x8 afr = *(const f16x8*)(Xrow + k0);
            #pragma unroll
            for (int g = 0; g < 4; ++g) {
                const f16x8 bfr = *(const f16x8*)(Wd + (long)(g * HH + u) * KP + k0);
                acc[g] = __builtin_amdgcn_mfma_f32_16x16x32_f16(afr, bfr, acc[g], 0, 0, 0);
            }
        }
    }
    // h part: kt 0..15 (K 320..831)
    if (step > 0) {
        const f16* Hrow = hs16 + ((long)arow * SS + s_prev) * H2 + dir * HH;
        #pragma unroll
        for (int kt = 0; kt < 16; ++kt) {
            const int k = kt * 32 + kgrp;
            const f16x8 afr = *(const f16x8*)(Hrow + k);
            #pragma unroll
            for (int g = 0; g < 4; ++g) {
                const f16x8 bfr = *(const f16x8*)(Wd + (long)(g * HH + u) * KP + EPX + k);
                acc[g] = __builtin_amdgcn_mfma_f32_16x16x32_f16(afr, bfr, acc[g], 0, 0, 0);
            }
        }
    }

    // gate epilogue: lane holds (i,f,g,o) of rows rbase..rbase+3, unit u
    const float* bi = dir ? bihB : bihF;
    const float* bh = dir ? bhhB : bhhF;
    const float bias0 = bi[u]          + bh[u];
    const float bias1 = bi[HH + u]     + bh[HH + u];
    const float bias2 = bi[2 * HH + u] + bh[2 * HH + u];
    const float bias3 = bi[3 * HH + u] + bh[3 * HH + u];
    const int rbase = (lane >> 4) * 4;
    #pragma unroll
    for (int i = 0; i < 4; ++i) {
        const int b = b0 + bt * 16 + rbase + i;
        const float zi = acc[0][i] + bias0;
        const float zf = acc[1][i] + bias1;
        const float zg = acc[2][i] + bias2;
        const float zo = acc[3][i] + bias3;
        float* cp = cbuf + ((long)dir * BB + b) * HH + u;
        float c = step ? *cp : 0.0f;
        c = sigmB(zf) * c + sigmB(zi) * tanhf(zg);
        *cp = c;
        const float h = sigmB(zo) * tanhf(c);
        hs16[((long)b * SS + s_eff) * H2 + dir * HH + u] = (f16)h;
    }
}

// ---------------------------------------------------------------------------
// Generic f16 MFMA GEMM: C[m][n] = act(sum_k A[m][k]*Bt[n][k]).
// Bt given row-per-output-column (padded rows). 64x64 tile, 4 waves (wave w
// owns rows m0+w*16). ACT=1: tanh. CF16: write f16 to Ch else fp32 to Cf.
// ---------------------------------------------------------------------------
template<int ACT, int CF16>
__global__ __launch_bounds__(256) void b_mfmaG(
    const f16* __restrict__ A16, long lda, long sAz,
    const f16* __restrict__ Bt, long ldb, long sBz,
    float* __restrict__ Cf, f16* __restrict__ Ch, long ldc, long sCz,
    int N, int K)
{
    const int n0 = blockIdx.x * 64;
    const int m0 = blockIdx.y * 64;
    const int tid = threadIdx.x;
    const int wave = tid >> 6, lane = tid & 63;
    const int l15 = lane & 15;
    const int kgrp = (lane >> 4) * 8;
    const f16* Ab = A16 + (long)blockIdx.z * sAz;
    const f16* Bb = Bt + (long)blockIdx.z * sBz;
    const f16* Arow = Ab + (long)(m0 + wave * 16 + l15) * lda;

    f32x4 acc[4];
    #pragma unroll
    for (int nt = 0; nt < 4; ++nt) acc[nt] = (f32x4){0.f, 0.f, 0.f, 0.f};

    for (int kt = 0; kt < K / 32; ++kt) {
        const int k0 = kt * 32 + kgrp;
        const f16x8 afr = *(const f16x8*)(Arow + k0);
        #pragma unroll
        for (int nt = 0; nt < 4; ++nt) {
            const f16x8 bfr = *(const f16x8*)(Bb + (long)(n0 + nt * 16 + l15) * ldb + k0);
            acc[nt] = __builtin_amdgcn_mfma_f32_16x16x32_f16(afr, bfr, acc[nt], 0, 0, 0);
        }
    }

    const long zc = (long)blockIdx.z * sCz;
    const int rbase = (lane >> 4) * 4;
    #pragma unroll
    for (int nt = 0; nt < 4; ++nt) {
        const int n = n0 + nt * 16 + l15;
        if (n < N) {
            #pragma unroll
            for (int i = 0; i < 4; ++i) {
                const int m = m0 + wave * 16 + rbase + i;
                float val = acc[nt][i];
                if (ACT == 1) val = tanhf(val);
                if (CF16) Ch[zc + (long)m * ldc + n] = (f16)val;
                else      Cf[zc + (long)m * ldc + n] = val;
            }
        }
    }
}

// attlog[b,r,s] = sum_a pre16[b,s,a] * ws2[r,a]
__global__ __launch_bounds__(256) void b_attlog(
    const f16* __restrict__ pre16, const float* __restrict__ ws2,
    float* __restrict__ attlog)
{
    const int idx = blockIdx.x * 256 + threadIdx.x;
    if (idx >= BB * RR * SS) return;
    const int s = idx & 63, r = (idx >> 6) & 7, b = idx >> 9;
    const f16* p = pre16 + ((long)b * SS + s) * DA;
    const float* w = ws2 + (long)r * DA;
    float acc = 0.0f;
    for (int a = 0; a < DA; ++a) acc = fmaf((float)p[a], w[a], acc);
    attlog[idx] = acc;
}

// softmax over s per (b,r)
__global__ __launch_bounds__(256) void b_soft(
    const float* __restrict__ attlog, float* __restrict__ att_out)
{
    const int idx = blockIdx.x * 256 + threadIdx.x;
    if (idx >= BB * RR) return;
    const float* L = attlog + (long)idx * SS;
    float mx = L[0];
    for (int s = 1; s < SS; ++s) mx = fmaxf(mx, L[s]);
    float sm = 0.0f;
    for (int s = 0; s < SS; ++s) sm += expf(L[s] - mx);
    for (int s = 0; s < SS; ++s)
        att_out[(long)idx * SS + s] = expf(L[s] - mx) / sm;
}

// sem16[b,r,d] = sum_s att[b,r,s] * hs16[b][s][d]
__global__ __launch_bounds__(256) void b_sem(
    const float* __restrict__ att, const f16* __restrict__ hs16,
    f16* __restrict__ sem16)
{
    const long idx = (long)blockIdx.x * 256 + threadIdx.x;
    if (idx >= (long)BB * RR * H2) return;
    const int d = (int)(idx & 1023);
    const int r = (int)((idx >> 10) & 7);
    const int b = (int)(idx >> 13);
    const float* aw = att + ((long)b * RR + r) * SS;
    float acc = 0.0f;
    for (int s = 0; s < SS; ++s)
        acc = fmaf(aw[s], (float)hs16[((long)b * SS + s) * H2 + d], acc);
    sem16[idx] = (f16)acc;
}

// ---------------------------------------------------------------------------
// Dynamic routing (reads pred fp32 from d_out)
// ---------------------------------------------------------------------------
__global__ __launch_bounds__(256) void b_route(
    const float* __restrict__ pred,
    float* __restrict__ cls_out, float* __restrict__ routes_out)
{
    __shared__ float predS[RR * CP];
    __shared__ float logitS[RR * CC];
    __shared__ float routeS[RR * CC];
    __shared__ float preactS[CP];
    __shared__ float vS[CP];
    __shared__ float scaleS[CC];
    __shared__ float rmax[RR], rsum[RR];
    const int b = blockIdx.x, tid = threadIdx.x;
    const float* ps = pred + (long)b * RR * CP;
    for (int i = tid; i < RR * CP; i += 256) predS[i] = ps[i];
    for (int i = tid; i < RR * CC; i += 256) logitS[i] = 0.0f;
    __syncthreads();

    for (int it = 0; it < 3; ++it) {
        if (tid < RR) {
            float mx = -1e30f;
            for (int c = 0; c < CC; ++c) mx = fmaxf(mx, logitS[tid * CC + c]);
            float sm = 0.0f;
            for (int c = 0; c < CC; ++c) sm += expf(logitS[tid * CC + c] - mx);
            rmax[tid] = mx; rsum[tid] = sm;
        }
        __syncthreads();
        for (int i = tid; i < RR * CC; i += 256) {
            const int r = i / CC;
            routeS[i] = expf(logitS[i] - rmax[r]) / rsum[r];
        }
        __syncthreads();
        for (int cp = tid; cp < CP; cp += 256) {
            const int c = cp >> 4;
            float a = 0.0f;
            #pragma unroll
            for (int r = 0; r < RR; ++r)
                a = fmaf(routeS[r * CC + c], predS[r * CP + cp], a);
            preactS[cp] = a;
        }
        __syncthreads();
        for (int c = tid; c < CC; c += 256) {
            float n2 = 0.0f;
            #pragma unroll
            for (int p = 0; p < PP; ++p) { const float x = preactS[c * PP + p]; n2 = fmaf(x, x, n2); }
            scaleS[c] = (n2 / (1.0f + n2)) / sqrtf(n2 + 1e-9f);
        }
        __syncthreads();
        for (int cp = tid; cp < CP; cp += 256) vS[cp] = preactS[cp] * scaleS[cp >> 4];
        __syncthreads();
        for (int i = tid; i < RR * CC; i += 256) {
            const int r = i / CC, c = i % CC;
            float a = 0.0f;
            #pragma unroll
            for (int p = 0; p < PP; ++p)
                a = fmaf(predS[r * CP + c * PP + p], vS[c * PP + p], a);
            logitS[i] += a;
        }
        __syncthreads();
    }

    for (int i = tid; i < RR * CC; i += 256)
        routes_out[(long)b * RR * CC + i] = routeS[i];
    for (int c = tid; c < CC; c += 256) {
        float n2 = 0.0f;
        #pragma unroll
        for (int p = 0; p < PP; ++p) { const float x = vS[c * PP + p]; n2 = fmaf(x, x, n2); }
        cls_out[(long)b * CC + c] = sqrtf(n2);
    }
}

// ---------------------------------------------------------------------------
extern "C" void kernel_launch(void* const* d_in, const int* in_sizes, int n_in,
                              void* d_out, int out_size, void* d_ws, size_t ws_size,
                              hipStream_t stream)
{
    (void)in_sizes; (void)n_in; (void)out_size;
    const int*   ids   = (const int*)d_in[0];
    const float* emb   = (const float*)d_in[2];
    const float* wih_f = (const float*)d_in[3];
    const float* whh_f = (const float*)d_in[4];
    const float* bih_f = (const float*)d_in[5];
    const float* bhh_f = (const float*)d_in[6];
    const float* wih_b = (const float*)d_in[7];
    const float* whh_b = (const float*)d_in[8];
    const float* bih_b = (const float*)d_in[9];
    const float* bhh_b = (const float*)d_in[10];
    const float* ws1   = (const float*)d_in[11];
    const float* ws2   = (const float*)d_in[12];
    const float* caps  = (const float*)d_in[13];
    float* out = (float*)d_out;   // fp32 outputs

    // Workspace (word offsets). capsT16 aliases [0 .. 9,961,472) after semB.
    float* ws = (float*)d_ws;
    f16*  hs16   = (f16*)ws;                          // 8,388,608 w
    float* cbuf  = ws + 8388608;                      //   262,144 w
    f16*  X16    = (f16*)(ws + 8650752);              // 2,621,440 w
    f16*  W16    = (f16*)(ws + 11272192);             // 1,703,936 w
    f16*  ws1_16 = (f16*)(ws + 12976128);             //   196,608 w (384x1024)
    f16*  sem16  = (f16*)(ws + 13172736);             // 1,048,576 w
    float* attlog = ws + 14221312;                    //   131,072 w
    f16*  pre16  = X16;                               // alias (X16/W16 dead post-LSTM)
    f16*  capsT16 = (f16*)ws;                         // alias (hs16/cbuf/pre16 dead)
    const size_t need = (size_t)(14221312 + 131072) * 4;
    if (ws_size < need) return;

    // Stage inputs
    b_gather<<<(int)(((long)SS * BB * EPX + 255) / 256), 256, 0, stream>>>(ids, emb, X16);
    b_packw<<<(int)(((long)2 * 2048 * KP + 255) / 256), 256, 0, stream>>>(
        wih_f, whh_f, wih_b, whh_b, W16);
    b_packws1<<<(384 * 1024) / 256, 256, 0, stream>>>(ws1, ws1_16);

    // Bidirectional LSTM: 256 blocks per step
    for (int step = 0; step < SS; ++step)
        b_step<<<dim3(8, 16, 2), 256, 0, stream>>>(
            X16, hs16, W16, cbuf, bih_f, bhh_f, bih_b, bhh_b, step);

    // pre16 = tanh(hs16 @ ws1^T)  [M=16384, N=350, K=1024], f16 out
    b_mfmaG<1, 1><<<dim3(6, 256, 1), 256, 0, stream>>>(
        hs16, H2, 0, ws1_16, H2, 0, nullptr, pre16, DA, 0, DA, H2);

    b_attlog<<<512, 256, 0, stream>>>(pre16, ws2, attlog);
    b_soft<<<8, 256, 0, stream>>>(attlog, out + ATT_OFF);
    b_sem<<<8192, 256, 0, stream>>>(out + ATT_OFF, hs16, sem16);

    // caps -> capsT16 (after semB: hs16 region dead)
    b_packcapsT<<<dim3(32, 76, 8), 256, 0, stream>>>(caps, capsT16);

    // pred = sem16 @ caps  [M=256, N=2400, K=1024] x8 (z=r), fp32 out
    b_mfmaG<0, 0><<<dim3(38, 4, 8), 256, 0, stream>>>(
        sem16, (long)RR * H2, H2, capsT16, H2, (long)2432 * H2,
        out + PRED_OFF, nullptr, (long)RR * CP, CP, CP, H2);

    b_route<<<BB, 256, 0, stream>>>(out + PRED_OFF, out + CL_OFF, out + ROUTES_OFF);
}

// Round 12
// 1523.765 us; speedup vs baseline: 2.3280x; 1.0159x over previous
//
#include <hip/hip_runtime.h>
#include <hip/hip_bf16.h>
#include <math.h>

// Sizes
#define BB 256
#define SS 64
#define EE 300
#define EPX 320   // X padded
#define KP 832    // 320 + 512
#define VV 30000
#define HH 512
#define H2 1024
#define DA 350
#define RR 8
#define CC 150
#define PP 16
#define CP 2400

// Output layout (elements, fp32)
#define ATT_OFF    0L
#define CL_OFF     131072L
#define PRED_OFF   169472L
#define ROUTES_OFF 5084672L

typedef _Float16 f16;
typedef f16  f16x8 __attribute__((ext_vector_type(8)));
typedef float f32x4 __attribute__((ext_vector_type(4)));

static __device__ __forceinline__ float sigmC(float x) { return 1.0f / (1.0f + expf(-x)); }

// ---------------------------------------------------------------------------
// X16[s][b][320] = f16(emb[ids[b][s]]), pad 300..319 = 0
// ---------------------------------------------------------------------------
__global__ __launch_bounds__(256) void c_gather(
    const int* __restrict__ ids, const float* __restrict__ emb, f16* __restrict__ X16)
{
    const long idx = (long)blockIdx.x * 256 + threadIdx.x;
    if (idx >= (long)SS * BB * EPX) return;
    const int e = (int)(idx % EPX);
    const int row = (int)(idx / EPX);
    const int s = row >> 8, b = row & 255;
    int tok = ids[(long)b * SS + s];
    if ((unsigned)tok >= (unsigned)VV) tok = 0;
    X16[idx] = (e < EE) ? (f16)emb[(long)tok * EE + e] : (f16)0.0f;
}

// W16[dir][j][832], j = gate*512+unit: k<300 wih, <320 zero, else whh
__global__ __launch_bounds__(256) void c_packw(
    const float* __restrict__ wihF, const float* __restrict__ whhF,
    const float* __restrict__ wihB, const float* __restrict__ whhB,
    f16* __restrict__ W16)
{
    const long idx = (long)blockIdx.x * 256 + threadIdx.x;
    if (idx >= (long)2 * 2048 * KP) return;
    const int dir = (int)(idx / (2048 * KP));
    const int rem = (int)(idx % (2048 * KP));
    const int j = rem / KP, k = rem % KP;
    const float* wih = dir ? wihB : wihF;
    const float* whh = dir ? whhB : whhF;
    float v;
    if (k < EE)        v = wih[(long)j * EE + k];
    else if (k < EPX)  v = 0.0f;
    else               v = whh[(long)j * HH + (k - EPX)];
    W16[idx] = (f16)v;
}

// ws1_16[384][1024], rows >= 350 zero
__global__ __launch_bounds__(256) void c_packws1(
    const float* __restrict__ ws1, f16* __restrict__ w)
{
    const int idx = blockIdx.x * 256 + threadIdx.x;
    if (idx >= 384 * 1024) return;
    const int j = idx >> 10;
    w[idx] = (j < DA) ? (f16)ws1[idx] : (f16)0.0f;
}

// capsT16[r][2432][1024] transposed; rows >= 2400 zero. LDS 32x32 tiles.
__global__ __launch_bounds__(256) void c_packcapsT(
    const float* __restrict__ caps, f16* __restrict__ capsT)
{
    __shared__ float t[32][33];
    const int r = blockIdx.z, k0 = blockIdx.x * 32, n0 = blockIdx.y * 32;
    const int tx = threadIdx.x & 31, ty = threadIdx.x >> 5;
    #pragma unroll
    for (int p = 0; p < 4; ++p) {
        const int k = k0 + ty + p * 8;
        const int n = n0 + tx;
        t[ty + p * 8][tx] = (n < CP) ? caps[((long)r * H2 + k) * CP + n] : 0.0f;
    }
    __syncthreads();
    #pragma unroll
    for (int p = 0; p < 4; ++p) {
        const int n = n0 + ty + p * 8;
        if (n < 2432)
            capsT[((long)r * 2432 + n) * H2 + k0 + tx] = (f16)t[tx][ty + p * 8];
    }
}

// ---------------------------------------------------------------------------
// LSTM step, K-split x2. Block = 32b x 16u, 4 waves: wave = bt + 2*kh.
// Each wave: 16x16 tile x 4 gates over K-half (416 = 13 kt). Partials of
// kh=1 go through LDS; waves 0,1 reduce + gate epilogue.
// grid (8, 32, 2) = 512 blocks = 2 waves/SIMD.
// ---------------------------------------------------------------------------
__global__ __launch_bounds__(256) void c_step(
    const f16* __restrict__ X16, f16* __restrict__ hs16,
    const f16* __restrict__ W16, float* __restrict__ cbuf,
    const float* __restrict__ bihF, const float* __restrict__ bhhF,
    const float* __restrict__ bihB, const float* __restrict__ bhhB,
    int step)
{
    __shared__ f32x4 part[2][64][4];   // 8 KB: kh=1 partials [bt][lane][g]
    const int dir = blockIdx.z;
    const int b0  = blockIdx.x * 32;
    const int u0  = blockIdx.y * 16;
    const int s_eff  = dir ? (SS - 1 - step) : step;
    const int s_prev = dir ? (s_eff + 1) : (s_eff - 1);
    const int tid = threadIdx.x;
    const int wave = tid >> 6, lane = tid & 63;
    const int bt = wave & 1, kh = wave >> 1;
    const int l15 = lane & 15;
    const int kgrp = (lane >> 4) * 8;
    const int arow = b0 + bt * 16 + l15;
    const int u = u0 + l15;

    f32x4 acc[4];
    #pragma unroll
    for (int g = 0; g < 4; ++g) acc[g] = (f32x4){0.f, 0.f, 0.f, 0.f};

    const f16* Wd = W16 + (long)dir * 2048 * KP;
    const f16* Xrow = X16 + ((long)s_eff * BB + arow) * EPX;
    const f16* Hrow = hs16 + ((long)arow * SS + s_prev) * H2 + dir * HH;

    if (kh == 0) {
        // X part: kt 0..9 (k 0..319)
        #pragma unroll
        for (int kt = 0; kt < 10; ++kt) {
            const int k0 = kt * 32 + kgrp;
            const f16x8 afr = *(const f16x8*)(Xrow + k0);
            #pragma unroll
            for (int g = 0; g < 4; ++g) {
                const f16x8 bfr = *(const f16x8*)(Wd + (long)(g * HH + u) * KP + k0);
                acc[g] = __builtin_amdgcn_mfma_f32_16x16x32_f16(afr, bfr, acc[g], 0, 0, 0);
            }
        }
        // h part: kt 0..2 (h k 0..95)
        if (step > 0) {
            #pragma unroll
            for (int kt = 0; kt < 3; ++kt) {
                const int k = kt * 32 + kgrp;
                const f16x8 afr = *(const f16x8*)(Hrow + k);
                #pragma unroll
                for (int g = 0; g < 4; ++g) {
                    const f16x8 bfr = *(const f16x8*)(Wd + (long)(g * HH + u) * KP + EPX + k);
                    acc[g] = __builtin_amdgcn_mfma_f32_16x16x32_f16(afr, bfr, acc[g], 0, 0, 0);
                }
            }
        }
    } else if (step > 0) {
        // h part: kt 3..15 (h k 96..511)
        #pragma unroll
        for (int kt = 3; kt < 16; ++kt) {
            const int k = kt * 32 + kgrp;
            const f16x8 afr = *(const f16x8*)(Hrow + k);
            #pragma unroll
            for (int g = 0; g < 4; ++g) {
                const f16x8 bfr = *(const f16x8*)(Wd + (long)(g * HH + u) * KP + EPX + k);
                acc[g] = __builtin_amdgcn_mfma_f32_16x16x32_f16(afr, bfr, acc[g], 0, 0, 0);
            }
        }
    }

    if (kh == 1) {
        #pragma unroll
        for (int g = 0; g < 4; ++g) part[bt][lane][g] = acc[g];
    }
    __syncthreads();
    if (kh == 0) {
        #pragma unroll
        for (int g = 0; g < 4; ++g) acc[g] += part[bt][lane][g];

        const float* bi = dir ? bihB : bihF;
        const float* bh = dir ? bhhB : bhhF;
        const float bias0 = bi[u]          + bh[u];
        const float bias1 = bi[HH + u]     + bh[HH + u];
        const float bias2 = bi[2 * HH + u] + bh[2 * HH + u];
        const float bias3 = bi[3 * HH + u] + bh[3 * HH + u];
        const int rbase = (lane >> 4) * 4;
        #pragma unroll
        for (int i = 0; i < 4; ++i) {
            const int b = b0 + bt * 16 + rbase + i;
            const float zi = acc[0][i] + bias0;
            const float zf = acc[1][i] + bias1;
            const float zg = acc[2][i] + bias2;
            const float zo = acc[3][i] + bias3;
            float* cp = cbuf + ((long)dir * BB + b) * HH + u;
            float c = step ? *cp : 0.0f;
            c = sigmC(zf) * c + sigmC(zi) * tanhf(zg);
            *cp = c;
            const float h = sigmC(zo) * tanhf(c);
            hs16[((long)b * SS + s_eff) * H2 + dir * HH + u] = (f16)h;
        }
    }
}

// ---------------------------------------------------------------------------
// f16 MFMA GEMM (unroll-4 kt loop for load ILP). C = act(A @ Bt^T).
// ---------------------------------------------------------------------------
template<int ACT, int CF16>
__global__ __launch_bounds__(256) void c_mfmaG(
    const f16* __restrict__ A16, long lda, long sAz,
    const f16* __restrict__ Bt, long ldb, long sBz,
    float* __restrict__ Cf, f16* __restrict__ Ch, long ldc, long sCz,
    int N, int K)
{
    const int n0 = blockIdx.x * 64;
    const int m0 = blockIdx.y * 64;
    const int tid = threadIdx.x;
    const int wave = tid >> 6, lane = tid & 63;
    const int l15 = lane & 15;
    const int kgrp = (lane >> 4) * 8;
    const f16* Ab = A16 + (long)blockIdx.z * sAz;
    const f16* Bb = Bt + (long)blockIdx.z * sBz;
    const f16* Arow = Ab + (long)(m0 + wave * 16 + l15) * lda;

    f32x4 acc[4];
    #pragma unroll
    for (int nt = 0; nt < 4; ++nt) acc[nt] = (f32x4){0.f, 0.f, 0.f, 0.f};

    #pragma unroll 4
    for (int kt = 0; kt < K / 32; ++kt) {
        const int k0 = kt * 32 + kgrp;
        const f16x8 afr = *(const f16x8*)(Arow + k0);
        #pragma unroll
        for (int nt = 0; nt < 4; ++nt) {
            const f16x8 bfr = *(const f16x8*)(Bb + (long)(n0 + nt * 16 + l15) * ldb + k0);
            acc[nt] = __builtin_amdgcn_mfma_f32_16x16x32_f16(afr, bfr, acc[nt], 0, 0, 0);
        }
    }

    const long zc = (long)blockIdx.z * sCz;
    const int rbase = (lane >> 4) * 4;
    #pragma unroll
    for (int nt = 0; nt < 4; ++nt) {
        const int n = n0 + nt * 16 + l15;
        if (n < N) {
            #pragma unroll
            for (int i = 0; i < 4; ++i) {
                const int m = m0 + wave * 16 + rbase + i;
                float val = acc[nt][i];
                if (ACT == 1) val = tanhf(val);
                if (CF16) Ch[zc + (long)m * ldc + n] = (f16)val;
                else      Cf[zc + (long)m * ldc + n] = val;
            }
        }
    }
}

// attlog[b,r,s] = sum_a pre16[b,s,a] * ws2[r,a]
__global__ __launch_bounds__(256) void c_attlog(
    const f16* __restrict__ pre16, const float* __restrict__ ws2,
    float* __restrict__ attlog)
{
    const int idx = blockIdx.x * 256 + threadIdx.x;
    if (idx >= BB * RR * SS) return;
    const int s = idx & 63, r = (idx >> 6) & 7, b = idx >> 9;
    const f16* p = pre16 + ((long)b * SS + s) * DA;
    const float* w = ws2 + (long)r * DA;
    float acc = 0.0f;
    for (int a = 0; a < DA; ++a) acc = fmaf((float)p[a], w[a], acc);
    attlog[idx] = acc;
}

// softmax over s per (b,r)
__global__ __launch_bounds__(256) void c_soft(
    const float* __restrict__ attlog, float* __restrict__ att_out)
{
    const int idx = blockIdx.x * 256 + threadIdx.x;
    if (idx >= BB * RR) return;
    const float* L = attlog + (long)idx * SS;
    float mx = L[0];
    for (int s = 1; s < SS; ++s) mx = fmaxf(mx, L[s]);
    float sm = 0.0f;
    for (int s = 0; s < SS; ++s) sm += expf(L[s] - mx);
    for (int s = 0; s < SS; ++s)
        att_out[(long)idx * SS + s] = expf(L[s] - mx) / sm;
}

// sem16: one block per b; hs16 read exactly once; acc[8][4] in registers.
// Thread owns 4 contiguous d (f16x4 = 8B coalesced reads).
typedef f16 f16x4 __attribute__((ext_vector_type(4)));
__global__ __launch_bounds__(256) void c_sem(
    const float* __restrict__ att, const f16* __restrict__ hs16,
    f16* __restrict__ sem16)
{
    __shared__ float aS[RR * SS];
    const int b = blockIdx.x, tid = threadIdx.x;
    for (int i = tid; i < RR * SS; i += 256) aS[i] = att[(long)b * RR * SS + i];
    __syncthreads();
    const int d0 = tid * 4;
    float acc[RR][4] = {};
    const f16* hb = hs16 + (long)b * SS * H2;
    for (int s = 0; s < SS; ++s) {
        const f16x4 hv = *(const f16x4*)(hb + s * H2 + d0);
        const float h0 = hv[0], h1 = hv[1], h2 = hv[2], h3 = hv[3];
        #pragma unroll
        for (int r = 0; r < RR; ++r) {
            const float a = aS[r * SS + s];
            acc[r][0] = fmaf(a, h0, acc[r][0]);
            acc[r][1] = fmaf(a, h1, acc[r][1]);
            acc[r][2] = fmaf(a, h2, acc[r][2]);
            acc[r][3] = fmaf(a, h3, acc[r][3]);
        }
    }
    #pragma unroll
    for (int r = 0; r < RR; ++r) {
        f16x4 o; o[0] = (f16)acc[r][0]; o[1] = (f16)acc[r][1];
        o[2] = (f16)acc[r][2]; o[3] = (f16)acc[r][3];
        *(f16x4*)(sem16 + ((long)b * RR + r) * H2 + d0) = o;
    }
}

// ---------------------------------------------------------------------------
// Dynamic routing (reads pred fp32 from d_out)
// ---------------------------------------------------------------------------
__global__ __launch_bounds__(256) void c_route(
    const float* __restrict__ pred,
    float* __restrict__ cls_out, float* __restrict__ routes_out)
{
    __shared__ float predS[RR * CP];
    __shared__ float logitS[RR * CC];
    __shared__ float routeS[RR * CC];
    __shared__ float preactS[CP];
    __shared__ float vS[CP];
    __shared__ float scaleS[CC];
    __shared__ float rmax[RR], rsum[RR];
    const int b = blockIdx.x, tid = threadIdx.x;
    const float* ps = pred + (long)b * RR * CP;
    for (int i = tid; i < RR * CP; i += 256) predS[i] = ps[i];
    for (int i = tid; i < RR * CC; i += 256) logitS[i] = 0.0f;
    __syncthreads();

    for (int it = 0; it < 3; ++it) {
        if (tid < RR) {
            float mx = -1e30f;
            for (int c = 0; c < CC; ++c) mx = fmaxf(mx, logitS[tid * CC + c]);
            float sm = 0.0f;
            for (int c = 0; c < CC; ++c) sm += expf(logitS[tid * CC + c] - mx);
            rmax[tid] = mx; rsum[tid] = sm;
        }
        __syncthreads();
        for (int i = tid; i < RR * CC; i += 256) {
            const int r = i / CC;
            routeS[i] = expf(logitS[i] - rmax[r]) / rsum[r];
        }
        __syncthreads();
        for (int cp = tid; cp < CP; cp += 256) {
            const int c = cp >> 4;
            float a = 0.0f;
            #pragma unroll
            for (int r = 0; r < RR; ++r)
                a = fmaf(routeS[r * CC + c], predS[r * CP + cp], a);
            preactS[cp] = a;
        }
        __syncthreads();
        for (int c = tid; c < CC; c += 256) {
            float n2 = 0.0f;
            #pragma unroll
            for (int p = 0; p < PP; ++p) { const float x = preactS[c * PP + p]; n2 = fmaf(x, x, n2); }
            scaleS[c] = (n2 / (1.0f + n2)) / sqrtf(n2 + 1e-9f);
        }
        __syncthreads();
        for (int cp = tid; cp < CP; cp += 256) vS[cp] = preactS[cp] * scaleS[cp >> 4];
        __syncthreads();
        for (int i = tid; i < RR * CC; i += 256) {
            const int r = i / CC, c = i % CC;
            float a = 0.0f;
            #pragma unroll
            for (int p = 0; p < PP; ++p)
                a = fmaf(predS[r * CP + c * PP + p], vS[c * PP + p], a);
            logitS[i] += a;
        }
        __syncthreads();
    }

    for (int i = tid; i < RR * CC; i += 256)
        routes_out[(long)b * RR * CC + i] = routeS[i];
    for (int c = tid; c < CC; c += 256) {
        float n2 = 0.0f;
        #pragma unroll
        for (int p = 0; p < PP; ++p) { const float x = vS[c * PP + p]; n2 = fmaf(x, x, n2); }
        cls_out[(long)b * CC + c] = sqrtf(n2);
    }
}

// ---------------------------------------------------------------------------
extern "C" void kernel_launch(void* const* d_in, const int* in_sizes, int n_in,
                              void* d_out, int out_size, void* d_ws, size_t ws_size,
                              hipStream_t stream)
{
    (void)in_sizes; (void)n_in; (void)out_size;
    const int*   ids   = (const int*)d_in[0];
    const float* emb   = (const float*)d_in[2];
    const float* wih_f = (const float*)d_in[3];
    const float* whh_f = (const float*)d_in[4];
    const float* bih_f = (const float*)d_in[5];
    const float* bhh_f = (const float*)d_in[6];
    const float* wih_b = (const float*)d_in[7];
    const float* whh_b = (const float*)d_in[8];
    const float* bih_b = (const float*)d_in[9];
    const float* bhh_b = (const float*)d_in[10];
    const float* ws1   = (const float*)d_in[11];
    const float* ws2   = (const float*)d_in[12];
    const float* caps  = (const float*)d_in[13];
    float* out = (float*)d_out;   // fp32 outputs

    // Workspace (word offsets); capsT16 aliases low region after c_sem.
    float* ws = (float*)d_ws;
    f16*  hs16   = (f16*)ws;                          // 8,388,608 w
    float* cbuf  = ws + 8388608;                      //   262,144 w
    f16*  X16    = (f16*)(ws + 8650752);              // 2,621,440 w
    f16*  W16    = (f16*)(ws + 11272192);             // 1,703,936 w
    f16*  ws1_16 = (f16*)(ws + 12976128);             //   196,608 w
    f16*  sem16  = (f16*)(ws + 13172736);             // 1,048,576 w
    float* attlog = ws + 14221312;                    //   131,072 w
    f16*  pre16  = X16;                               // alias (post-LSTM)
    f16*  capsT16 = (f16*)ws;                         // alias (post-sem)
    const size_t need = (size_t)(14221312 + 131072) * 4;
    if (ws_size < need) return;

    // Stage inputs
    c_gather<<<(int)(((long)SS * BB * EPX + 255) / 256), 256, 0, stream>>>(ids, emb, X16);
    c_packw<<<(int)(((long)2 * 2048 * KP + 255) / 256), 256, 0, stream>>>(
        wih_f, whh_f, wih_b, whh_b, W16);
    c_packws1<<<(384 * 1024) / 256, 256, 0, stream>>>(ws1, ws1_16);

    // Bidirectional LSTM: K-split step kernels, 512 blocks each
    for (int step = 0; step < SS; ++step)
        c_step<<<dim3(8, 32, 2), 256, 0, stream>>>(
            X16, hs16, W16, cbuf, bih_f, bhh_f, bih_b, bhh_b, step);

    // pre16 = tanh(hs16 @ ws1^T)  [M=16384, N=350, K=1024], f16 out
    c_mfmaG<1, 1><<<dim3(6, 256, 1), 256, 0, stream>>>(
        hs16, H2, 0, ws1_16, H2, 0, nullptr, pre16, DA, 0, DA, H2);

    c_attlog<<<512, 256, 0, stream>>>(pre16, ws2, attlog);
    c_soft<<<8, 256, 0, stream>>>(attlog, out + ATT_OFF);
    c_sem<<<BB, 256, 0, stream>>>(out + ATT_OFF, hs16, sem16);

    // caps -> capsT16 (hs16 region dead after c_sem)
    c_packcapsT<<<dim3(32, 76, 8), 256, 0, stream>>>(caps, capsT16);

    // pred = sem16 @ caps  [M=256, N=2400, K=1024] x8 (z=r), fp32 out
    c_mfmaG<0, 0><<<dim3(38, 4, 8), 256, 0, stream>>>(
        sem16, (long)RR * H2, H2, capsT16, H2, (long)2432 * H2,
        out + PRED_OFF, nullptr, (long)RR * CP, CP, CP, H2);

    c_route<<<BB, 256, 0, stream>>>(out + PRED_OFF, out + CL_OFF, out + ROUTES_OFF);
}